// Round 1
// baseline (1622.064 us; speedup 1.0000x reference)
//
#include <hip/hip_runtime.h>
#include <math.h>

#define B_ 16
#define C_ 256
#define CI_ 128
#define N_ 4096
#define M_ 1024
#define EPS_BN 1e-5f

// ---------------- workspace layout (float offsets) ----------------
#define OFF_WT  ((size_t)0)                      // 3*256*128 = 98304
#define OFF_Q   ((size_t)98304)                  // B*N*CI
#define OFF_PHI (OFF_Q   + (size_t)B_*N_*CI_)    // full-res phi conv
#define OFF_G   (OFF_PHI + (size_t)B_*N_*CI_)    // full-res g conv
#define OFF_K   (OFF_G   + (size_t)B_*N_*CI_)    // pooled phi  [B][M][CI]
#define OFF_V   (OFF_K   + (size_t)B_*M_*CI_)    // pooled g    [B][M][CI]
#define OFF_YA  (OFF_V   + (size_t)B_*M_*CI_)    // attention out [B][N][CI]
#define OFF_ST  (OFF_YA  + (size_t)B_*N_*CI_)    // 512 floats (sum, sumsq)
#define OFF_Y2  OFF_PHI                          // alias dead phi+g region: 16.7M <= 2*8.39M

// ---------------- k0: transpose projection weights [128][256] -> [256][128] ----
__global__ void k0_transpose_w(const float* __restrict__ w_th,
                               const float* __restrict__ w_ph,
                               const float* __restrict__ w_g,
                               float* __restrict__ wT) {
    int idx = blockIdx.x * 256 + threadIdx.x;   // 3*128*256 = 98304 total
    int proj = idx >> 15;
    int r = idx & 32767;
    int o = r >> 8;        // 0..127
    int c = r & 255;       // 0..255
    const float* src = (proj == 0) ? w_th : (proj == 1) ? w_ph : w_g;
    wT[((size_t)proj * 256 + c) * 128 + o] = src[o * 256 + c];
}

// ---------------- k1: projection GEMM: out[b][n][o] = sum_c x[b][c][n]*w[o][c] + bias[o]
// tile: 64 n x 128 o, K chunked by 32. thread: 8 o x 4 n.
__global__ __launch_bounds__(256) void k1_proj(
    const float* __restrict__ x, const float* __restrict__ wT,
    const float* __restrict__ b_th, const float* __restrict__ b_ph,
    const float* __restrict__ b_g,
    float* __restrict__ outQ, float* __restrict__ outPHI, float* __restrict__ outG) {
    __shared__ float xs[32][64];    // [c][n]
    __shared__ float wt[32][128];   // [c][o]
    int t = threadIdx.x;
    int ntile = blockIdx.x;   // 0..63
    int b = blockIdx.y;       // 0..15
    int proj = blockIdx.z;    // 0 theta->Q, 1 phi->PHI, 2 g->G
    const float* bias = (proj == 0) ? b_th : (proj == 1) ? b_ph : b_g;
    float* out = (proj == 0) ? outQ : (proj == 1) ? outPHI : outG;

    int i = t >> 4;           // 0..15
    int m = t & 15;           // 0..15
    int o8 = i * 8, n4 = m * 4;

    float acc[8][4];
#pragma unroll
    for (int j = 0; j < 8; j++) {
        float bv = bias[o8 + j];
#pragma unroll
        for (int k = 0; k < 4; k++) acc[j][k] = bv;
    }

    const float* xbase = x + (size_t)b * C_ * N_ + ntile * 64;
    const float* wbase = wT + (size_t)proj * 256 * 128;

    for (int c0 = 0; c0 < 256; c0 += 32) {
        __syncthreads();
#pragma unroll
        for (int r = 0; r < 2; r++) {            // x chunk: 32x64 = 512 f4
            int id = t + 256 * r;
            int row = id >> 4, col4 = (id & 15) * 4;
            *(float4*)&xs[row][col4] =
                *(const float4*)&xbase[(size_t)(c0 + row) * N_ + col4];
        }
#pragma unroll
        for (int r = 0; r < 4; r++) {            // w chunk: 32x128 = 1024 f4
            int id = t + 256 * r;
            int row = id >> 5, col4 = (id & 31) * 4;
            *(float4*)&wt[row][col4] =
                *(const float4*)&wbase[(size_t)(c0 + row) * 128 + col4];
        }
        __syncthreads();
#pragma unroll 4
        for (int cc = 0; cc < 32; cc++) {
            float4 xv = *(float4*)&xs[cc][n4];
            float4 w0 = *(float4*)&wt[cc][o8];
            float4 w1 = *(float4*)&wt[cc][o8 + 4];
            float wj[8] = {w0.x, w0.y, w0.z, w0.w, w1.x, w1.y, w1.z, w1.w};
            float xk[4] = {xv.x, xv.y, xv.z, xv.w};
#pragma unroll
            for (int j = 0; j < 8; j++)
#pragma unroll
                for (int k = 0; k < 4; k++) acc[j][k] += wj[j] * xk[k];
        }
    }
    float* obase = out + ((size_t)b * N_ + ntile * 64) * 128;
#pragma unroll
    for (int k = 0; k < 4; k++) {
        float4 s0 = {acc[0][k], acc[1][k], acc[2][k], acc[3][k]};
        float4 s1 = {acc[4][k], acc[5][k], acc[6][k], acc[7][k]};
        *(float4*)&obase[(size_t)(n4 + k) * 128 + o8] = s0;
        *(float4*)&obase[(size_t)(n4 + k) * 128 + o8 + 4] = s1;
    }
}

// ---------------- k2: 2x2 maxpool phi,g (full res [B][N][128]) -> [B][M][128]
__global__ void k2_pool(const float* __restrict__ phiF, const float* __restrict__ gF,
                        float* __restrict__ Kb, float* __restrict__ Vb) {
    int idx = blockIdx.x * 256 + threadIdx.x;   // 2 * 16*1024*32 f4
    int proj = idx >> 19;
    int r = idx & 524287;
    int o4 = (r & 31) * 4;
    int mp = (r >> 5) & 1023;
    int b = r >> 15;
    int hp = mp >> 5, wp = mp & 31;
    int n00 = hp * 128 + wp * 2;
    const float* base = (proj ? gF : phiF) + (size_t)b * N_ * 128;
    float4 a0 = *(const float4*)&base[(size_t)(n00)*128 + o4];
    float4 a1 = *(const float4*)&base[(size_t)(n00 + 1) * 128 + o4];
    float4 a2 = *(const float4*)&base[(size_t)(n00 + 64) * 128 + o4];
    float4 a3 = *(const float4*)&base[(size_t)(n00 + 65) * 128 + o4];
    float4 mx;
    mx.x = fmaxf(fmaxf(a0.x, a1.x), fmaxf(a2.x, a3.x));
    mx.y = fmaxf(fmaxf(a0.y, a1.y), fmaxf(a2.y, a3.y));
    mx.z = fmaxf(fmaxf(a0.z, a1.z), fmaxf(a2.z, a3.z));
    mx.w = fmaxf(fmaxf(a0.w, a1.w), fmaxf(a2.w, a3.w));
    float* dst = (proj ? Vb : Kb) + ((size_t)b * M_ + mp) * 128 + o4;
    *(float4*)dst = mx;
}

// ---------------- k3: flash attention (fp32). WG = (b, 32-query tile).
// thread: q = t>>3, col-group jj = t&7 owns O[q][jj*16..+15]; S phase same q, m4=jj*4.
__global__ __launch_bounds__(256) void k3_attn(
    const float* __restrict__ Q, const float* __restrict__ Kb,
    const float* __restrict__ Vb, float* __restrict__ Y) {
    __shared__ float Qs[32][132];
    __shared__ float Ks[32][132];
    __shared__ float Vs[32][132];
    int t = threadIdx.x;
    int qt = blockIdx.x;    // 0..127
    int b = blockIdx.y;
    int q = t >> 3;
    int jj = t & 7;
    int jj16 = jj * 16;

    const float* qbase = Q + ((size_t)b * N_ + qt * 32) * 128;
#pragma unroll
    for (int r = 0; r < 4; r++) {
        int id = t + 256 * r;
        int row = id >> 5, col4 = (id & 31) * 4;
        *(float4*)&Qs[row][col4] = *(const float4*)&qbase[(size_t)row * 128 + col4];
    }

    float acc[16];
#pragma unroll
    for (int k = 0; k < 16; k++) acc[k] = 0.f;
    float m_run = -1e30f, l_run = 0.f;

    const float* kbase = Kb + (size_t)b * M_ * 128;
    const float* vbase = Vb + (size_t)b * M_ * 128;
    int lanebase = (t & 63) & 56;

    for (int kc = 0; kc < 32; kc++) {
        __syncthreads();
#pragma unroll
        for (int r = 0; r < 4; r++) {
            int id = t + 256 * r;
            int row = id >> 5, col4 = (id & 31) * 4;
            *(float4*)&Ks[row][col4] =
                *(const float4*)&kbase[(size_t)(kc * 32 + row) * 128 + col4];
            *(float4*)&Vs[row][col4] =
                *(const float4*)&vbase[(size_t)(kc * 32 + row) * 128 + col4];
        }
        __syncthreads();

        int m4 = jj * 4;
        float sd[4] = {0.f, 0.f, 0.f, 0.f};
#pragma unroll 8
        for (int c4 = 0; c4 < 128; c4 += 4) {
            float4 qv = *(float4*)&Qs[q][c4];
#pragma unroll
            for (int j = 0; j < 4; j++) {
                float4 kv = *(float4*)&Ks[m4 + j][c4];
                sd[j] += qv.x * kv.x + qv.y * kv.y + qv.z * kv.z + qv.w * kv.w;
            }
        }
        // online softmax over row group of 8 lanes (reference has NO 1/sqrt(d) scale)
        float mx = fmaxf(fmaxf(sd[0], sd[1]), fmaxf(sd[2], sd[3]));
#pragma unroll
        for (int d = 1; d < 8; d <<= 1) mx = fmaxf(mx, __shfl_xor(mx, d));
        float new_m = fmaxf(m_run, mx);
        float alpha = __expf(m_run - new_m);
        float p4[4], ps = 0.f;
#pragma unroll
        for (int j = 0; j < 4; j++) { p4[j] = __expf(sd[j] - new_m); ps += p4[j]; }
#pragma unroll
        for (int d = 1; d < 8; d <<= 1) ps += __shfl_xor(ps, d);
        l_run = l_run * alpha + ps;
        m_run = new_m;
#pragma unroll
        for (int k = 0; k < 16; k++) acc[k] *= alpha;

#pragma unroll 8
        for (int mm = 0; mm < 32; mm++) {
            float p = __shfl(p4[mm & 3], lanebase + (mm >> 2));
            const float* vrow = &Vs[mm][jj16];
#pragma unroll
            for (int k = 0; k < 4; k++) {
                float4 vv = *(float4*)&vrow[k * 4];
                acc[k * 4 + 0] += p * vv.x;
                acc[k * 4 + 1] += p * vv.y;
                acc[k * 4 + 2] += p * vv.z;
                acc[k * 4 + 3] += p * vv.w;
            }
        }
    }
    float inv = 1.f / l_run;
    float* ybase = Y + ((size_t)b * N_ + qt * 32 + q) * 128 + jj16;
#pragma unroll
    for (int k = 0; k < 4; k++) {
        float4 ov = {acc[k * 4] * inv, acc[k * 4 + 1] * inv,
                     acc[k * 4 + 2] * inv, acc[k * 4 + 3] * inv};
        *(float4*)&ybase[k * 4] = ov;
    }
}

// ---------------- k4: W-conv GEMM y2[b][o][n] = sum_ci y[b][n][ci]*ww[o][ci] + wb[o]
// tile 64 o x 64 n, K=128 in two 64-chunks; fused per-channel sum/sumsq atomics.
__global__ __launch_bounds__(256) void k4_convw(
    const float* __restrict__ Y, const float* __restrict__ ww,
    const float* __restrict__ wb, float* __restrict__ Y2,
    float* __restrict__ stats) {
    __shared__ float wsT[64][68];
    __shared__ float ys[64][68];
    int t = threadIdx.x;
    int ntile = blockIdx.x;   // 0..63
    int ot = blockIdx.y;      // 0..3
    int b = blockIdx.z;

    const float* wbase = ww + (size_t)ot * 64 * 128;
    const float* ybase = Y + ((size_t)b * N_ + ntile * 64) * 128;

    int i = t >> 4;   // 0..15
    int m = t & 15;   // 0..15
    float acc[4][4];
#pragma unroll
    for (int j = 0; j < 4; j++)
#pragma unroll
        for (int k = 0; k < 4; k++) acc[j][k] = 0.f;

    for (int c0 = 0; c0 < 128; c0 += 64) {
        __syncthreads();
#pragma unroll
        for (int r = 0; r < 4; r++) {          // 64x64 = 1024 f4 each
            int id = t + 256 * r;
            int row = id >> 4, col4 = (id & 15) * 4;
            *(float4*)&wsT[row][col4] =
                *(const float4*)&wbase[(size_t)row * 128 + c0 + col4];
            *(float4*)&ys[row][col4] =
                *(const float4*)&ybase[(size_t)row * 128 + c0 + col4];
        }
        __syncthreads();
#pragma unroll 4
        for (int c4 = 0; c4 < 64; c4 += 4) {
            float4 wv[4], yv[4];
#pragma unroll
            for (int j = 0; j < 4; j++) wv[j] = *(float4*)&wsT[i + 16 * j][c4];
#pragma unroll
            for (int k = 0; k < 4; k++) yv[k] = *(float4*)&ys[m + 16 * k][c4];
#pragma unroll
            for (int j = 0; j < 4; j++)
#pragma unroll
                for (int k = 0; k < 4; k++)
                    acc[j][k] += wv[j].x * yv[k].x + wv[j].y * yv[k].y +
                                 wv[j].z * yv[k].z + wv[j].w * yv[k].w;
        }
    }

    float s1[4], s2[4];
#pragma unroll
    for (int j = 0; j < 4; j++) {
        float bv = wb[ot * 64 + i + 16 * j];
        s1[j] = 0.f; s2[j] = 0.f;
#pragma unroll
        for (int k = 0; k < 4; k++) {
            float v = acc[j][k] + bv;
            acc[j][k] = v;
            s1[j] += v; s2[j] += v * v;
        }
    }
#pragma unroll
    for (int d = 1; d < 16; d <<= 1) {
#pragma unroll
        for (int j = 0; j < 4; j++) {
            s1[j] += __shfl_xor(s1[j], d);
            s2[j] += __shfl_xor(s2[j], d);
        }
    }
    if (m == 0) {
#pragma unroll
        for (int j = 0; j < 4; j++) {
            int o = ot * 64 + i + 16 * j;
            atomicAdd(&stats[o], s1[j]);
            atomicAdd(&stats[256 + o], s2[j]);
        }
    }
    float* obase = Y2 + (size_t)b * C_ * N_;
#pragma unroll
    for (int j = 0; j < 4; j++)
#pragma unroll
        for (int k = 0; k < 4; k++)
            obase[(size_t)(ot * 64 + i + 16 * j) * N_ + ntile * 64 + m + 16 * k] =
                acc[j][k];
}

// ---------------- k6: BN (training stats) + affine + residual
__global__ void k6_bn(const float* __restrict__ Y2, const float* __restrict__ x,
                      const float* __restrict__ stats,
                      const float* __restrict__ gamma, const float* __restrict__ beta,
                      float* __restrict__ outp) {
    int idx = blockIdx.x * 256 + threadIdx.x;   // f4 index
    size_t base = (size_t)idx * 4;
    int o = (int)((base >> 12) & 255);
    const float cnt = (float)(B_ * N_);
    float mean = stats[o] / cnt;
    float var = stats[256 + o] / cnt - mean * mean;
    float scale = gamma[o] * rsqrtf(var + EPS_BN);
    float shift = beta[o] - mean * scale;
    float4 yv = *(const float4*)&Y2[base];
    float4 xv = *(const float4*)&x[base];
    float4 ov;
    ov.x = yv.x * scale + shift + xv.x;
    ov.y = yv.y * scale + shift + xv.y;
    ov.z = yv.z * scale + shift + xv.z;
    ov.w = yv.w * scale + shift + xv.w;
    *(float4*)&outp[base] = ov;
}

extern "C" void kernel_launch(void* const* d_in, const int* in_sizes, int n_in,
                              void* d_out, int out_size, void* d_ws, size_t ws_size,
                              hipStream_t stream) {
    const float* x    = (const float*)d_in[0];
    const float* g_w  = (const float*)d_in[1];
    const float* g_b  = (const float*)d_in[2];
    const float* th_w = (const float*)d_in[3];
    const float* th_b = (const float*)d_in[4];
    const float* ph_w = (const float*)d_in[5];
    const float* ph_b = (const float*)d_in[6];
    const float* w_w  = (const float*)d_in[7];
    const float* w_b  = (const float*)d_in[8];
    const float* gam  = (const float*)d_in[9];
    const float* bet  = (const float*)d_in[10];

    float* ws   = (float*)d_ws;
    float* wT   = ws + OFF_WT;
    float* Qb   = ws + OFF_Q;
    float* PHIb = ws + OFF_PHI;
    float* Gb   = ws + OFF_G;
    float* Kb   = ws + OFF_K;
    float* Vb   = ws + OFF_V;
    float* YA   = ws + OFF_YA;
    float* ST   = ws + OFF_ST;
    float* Y2   = ws + OFF_Y2;
    float* outp = (float*)d_out;

    hipMemsetAsync(ST, 0, 512 * sizeof(float), stream);
    k0_transpose_w<<<384, 256, 0, stream>>>(th_w, ph_w, g_w, wT);
    k1_proj<<<dim3(64, 16, 3), 256, 0, stream>>>(x, wT, th_b, ph_b, g_b, Qb, PHIb, Gb);
    k2_pool<<<4096, 256, 0, stream>>>(PHIb, Gb, Kb, Vb);
    k3_attn<<<dim3(128, 16), 256, 0, stream>>>(Qb, Kb, Vb, YA);
    k4_convw<<<dim3(64, 4, 16), 256, 0, stream>>>(YA, w_w, w_b, Y2, ST);
    k6_bn<<<16384, 256, 0, stream>>>(Y2, x, ST, gam, bet, outp);
}

// Round 3
// 510.700 us; speedup vs baseline: 3.1762x; 3.1762x over previous
//
#include <hip/hip_runtime.h>
#include <math.h>

#define B_ 16
#define C_ 256
#define CI_ 128
#define N_ 4096
#define M_ 1024
#define EPS_BN 1e-5f

typedef __attribute__((ext_vector_type(8))) short short8;
typedef __attribute__((ext_vector_type(4))) float float4v;

__device__ __forceinline__ unsigned short f2bf(float f) {
    unsigned int u = __builtin_bit_cast(unsigned int, f);
    u += 0x7fff + ((u >> 16) & 1);
    return (unsigned short)(u >> 16);
}
__device__ __forceinline__ float bf2f(unsigned short h) {
    unsigned int u = ((unsigned int)h) << 16;
    return __builtin_bit_cast(float, u);
}

// ---------------- workspace layout (bytes) ----------------
#define OFF_WT  ((size_t)0)
#define OFF_Q   ((size_t)393216)
#define OFF_PHI (OFF_Q   + (size_t)16777216)
#define OFF_G   (OFF_PHI + (size_t)16777216)
#define OFF_KP  (OFF_G   + (size_t)16777216)
#define OFF_VT  (OFF_KP  + (size_t)4194304)
#define OFF_YA  (OFF_VT  + (size_t)4194304)
#define OFF_ST  (OFF_YA  + (size_t)33554432)
#define OFF_Y2  OFF_Q

// ---------------- k0: transpose projection weights [128][256] -> [256][128]
__global__ void k0_transpose_w(const float* __restrict__ w_th,
                               const float* __restrict__ w_ph,
                               const float* __restrict__ w_g,
                               float* __restrict__ wT) {
    int idx = blockIdx.x * 256 + threadIdx.x;
    int proj = idx >> 15;
    int r = idx & 32767;
    int o = r >> 8;
    int c = r & 255;
    const float* src = (proj == 0) ? w_th : (proj == 1) ? w_ph : w_g;
    wT[((size_t)proj * 256 + c) * 128 + o] = src[o * 256 + c];
}

// ---------------- k1: projection GEMM -> bf16 out [b][n][o]
__global__ __launch_bounds__(256) void k1_proj(
    const float* __restrict__ x, const float* __restrict__ wT,
    const float* __restrict__ b_th, const float* __restrict__ b_ph,
    const float* __restrict__ b_g,
    unsigned short* __restrict__ outQ, unsigned short* __restrict__ outPHI,
    unsigned short* __restrict__ outG) {
    __shared__ float xs[32][64];
    __shared__ float wt[32][128];
    int t = threadIdx.x;
    int ntile = blockIdx.x;
    int b = blockIdx.y;
    int proj = blockIdx.z;
    const float* bias = (proj == 0) ? b_th : (proj == 1) ? b_ph : b_g;
    unsigned short* out = (proj == 0) ? outQ : (proj == 1) ? outPHI : outG;

    int i = t >> 4;
    int m = t & 15;
    int o8 = i * 8, n4 = m * 4;

    float acc[8][4];
#pragma unroll
    for (int j = 0; j < 8; j++) {
        float bv = bias[o8 + j];
#pragma unroll
        for (int k = 0; k < 4; k++) acc[j][k] = bv;
    }

    const float* xbase = x + (size_t)b * C_ * N_ + ntile * 64;
    const float* wbase = wT + (size_t)proj * 256 * 128;

    for (int c0 = 0; c0 < 256; c0 += 32) {
        __syncthreads();
#pragma unroll
        for (int r = 0; r < 2; r++) {
            int id = t + 256 * r;
            int row = id >> 4, col4 = (id & 15) * 4;
            *(float4*)&xs[row][col4] =
                *(const float4*)&xbase[(size_t)(c0 + row) * N_ + col4];
        }
#pragma unroll
        for (int r = 0; r < 4; r++) {
            int id = t + 256 * r;
            int row = id >> 5, col4 = (id & 31) * 4;
            *(float4*)&wt[row][col4] =
                *(const float4*)&wbase[(size_t)(c0 + row) * 128 + col4];
        }
        __syncthreads();
#pragma unroll 4
        for (int cc = 0; cc < 32; cc++) {
            float4 xv = *(float4*)&xs[cc][n4];
            float4 w0 = *(float4*)&wt[cc][o8];
            float4 w1 = *(float4*)&wt[cc][o8 + 4];
            float wj[8] = {w0.x, w0.y, w0.z, w0.w, w1.x, w1.y, w1.z, w1.w};
            float xk[4] = {xv.x, xv.y, xv.z, xv.w};
#pragma unroll
            for (int j = 0; j < 8; j++)
#pragma unroll
                for (int k = 0; k < 4; k++) acc[j][k] += wj[j] * xk[k];
        }
    }
    unsigned short* obase = out + ((size_t)b * N_ + ntile * 64) * 128;
#pragma unroll
    for (int k = 0; k < 4; k++) {
        unsigned int pk[4];
#pragma unroll
        for (int j = 0; j < 4; j++) {
            unsigned short lo = f2bf(acc[2 * j][k]);
            unsigned short hi = f2bf(acc[2 * j + 1][k]);
            pk[j] = (unsigned int)lo | ((unsigned int)hi << 16);
        }
        uint4 v = {pk[0], pk[1], pk[2], pk[3]};
        *(uint4*)&obase[(size_t)(n4 + k) * 128 + o8] = v;
    }
}

// ---------------- k2k: 2x2 maxpool PHI (bf16) -> Kp [b][m][128]
__global__ void k2k_pool(const unsigned short* __restrict__ phiF,
                         unsigned short* __restrict__ Kp) {
    int idx = blockIdx.x * 256 + threadIdx.x;   // 16*1024*16
    int c8 = idx & 15;
    int mp = (idx >> 4) & 1023;
    int b = idx >> 14;
    int hp = mp >> 5, wp = mp & 31;
    int n00 = hp * 128 + wp * 2;
    const unsigned short* base = phiF + (size_t)b * N_ * 128 + c8 * 8;
    uint4 r0 = *(const uint4*)&base[(size_t)n00 * 128];
    uint4 r1 = *(const uint4*)&base[(size_t)(n00 + 1) * 128];
    uint4 r2 = *(const uint4*)&base[(size_t)(n00 + 64) * 128];
    uint4 r3 = *(const uint4*)&base[(size_t)(n00 + 65) * 128];
    const unsigned int* a0 = &r0.x; const unsigned int* a1 = &r1.x;
    const unsigned int* a2 = &r2.x; const unsigned int* a3 = &r3.x;
    unsigned int res[4];
#pragma unroll
    for (int j = 0; j < 4; j++) {
        float vlo = fmaxf(fmaxf(bf2f((unsigned short)(a0[j] & 0xffff)),
                                bf2f((unsigned short)(a1[j] & 0xffff))),
                          fmaxf(bf2f((unsigned short)(a2[j] & 0xffff)),
                                bf2f((unsigned short)(a3[j] & 0xffff))));
        float vhi = fmaxf(fmaxf(bf2f((unsigned short)(a0[j] >> 16)),
                                bf2f((unsigned short)(a1[j] >> 16))),
                          fmaxf(bf2f((unsigned short)(a2[j] >> 16)),
                                bf2f((unsigned short)(a3[j] >> 16))));
        res[j] = (unsigned int)f2bf(vlo) | ((unsigned int)f2bf(vhi) << 16);
    }
    uint4 v = {res[0], res[1], res[2], res[3]};
    *(uint4*)&Kp[((size_t)b * M_ + mp) * 128 + c8 * 8] = v;
}

// ---------------- k2v: 2x2 maxpool G (bf16) + transpose -> Vt [b][128][M]
__global__ __launch_bounds__(256) void k2v_poolT(const unsigned short* __restrict__ gF,
                                                 unsigned short* __restrict__ Vt) {
    __shared__ unsigned short tile[64][136];   // [m_local][c]
    int t = threadIdx.x;
    int mb = blockIdx.x;   // 0..15 (64-m block)
    int b = blockIdx.y;
#pragma unroll
    for (int it = 0; it < 4; it++) {
        int idx = t + 256 * it;
        int ml = idx >> 4;        // 0..63
        int c8 = idx & 15;
        int mp = mb * 64 + ml;
        int hp = mp >> 5, wp = mp & 31;
        int n00 = hp * 128 + wp * 2;
        const unsigned short* base = gF + (size_t)b * N_ * 128 + c8 * 8;
        uint4 r0 = *(const uint4*)&base[(size_t)n00 * 128];
        uint4 r1 = *(const uint4*)&base[(size_t)(n00 + 1) * 128];
        uint4 r2 = *(const uint4*)&base[(size_t)(n00 + 64) * 128];
        uint4 r3 = *(const uint4*)&base[(size_t)(n00 + 65) * 128];
        const unsigned int* a0 = &r0.x; const unsigned int* a1 = &r1.x;
        const unsigned int* a2 = &r2.x; const unsigned int* a3 = &r3.x;
#pragma unroll
        for (int j = 0; j < 4; j++) {
            float lo = fmaxf(fmaxf(bf2f((unsigned short)(a0[j] & 0xffff)),
                                   bf2f((unsigned short)(a1[j] & 0xffff))),
                             fmaxf(bf2f((unsigned short)(a2[j] & 0xffff)),
                                   bf2f((unsigned short)(a3[j] & 0xffff))));
            float hi = fmaxf(fmaxf(bf2f((unsigned short)(a0[j] >> 16)),
                                   bf2f((unsigned short)(a1[j] >> 16))),
                             fmaxf(bf2f((unsigned short)(a2[j] >> 16)),
                                   bf2f((unsigned short)(a3[j] >> 16))));
            tile[ml][c8 * 8 + 2 * j] = f2bf(lo);
            tile[ml][c8 * 8 + 2 * j + 1] = f2bf(hi);
        }
    }
    __syncthreads();
#pragma unroll
    for (int it = 0; it < 4; it++) {
        int idx = t + 256 * it;
        int c = idx >> 3;        // 0..127
        int m8 = idx & 7;
        unsigned int pk[4];
#pragma unroll
        for (int j = 0; j < 4; j++) {
            unsigned short lo = tile[m8 * 8 + 2 * j][c];
            unsigned short hi = tile[m8 * 8 + 2 * j + 1][c];
            pk[j] = (unsigned int)lo | ((unsigned int)hi << 16);
        }
        uint4 v = {pk[0], pk[1], pk[2], pk[3]};
        *(uint4*)&Vt[((size_t)b * 128 + c) * M_ + mb * 64 + m8 * 8] = v;
    }
}

// ---------------- k3: bf16 MFMA flash attention
// WG = 4 waves, 128 q; wave: 32 q (2 q-tiles of 16), m-chunks of 32.
// S^T = K·Q^T (A=K LDS frag, B=Q reg frag); softmax in C-layout;
// P^T via per-wave LDS; O^T = V^T·P^T (A=Vt LDS frag, B=P^T LDS frag).
__global__ __launch_bounds__(256, 2) void k3_attn(
    const unsigned short* __restrict__ Q, const unsigned short* __restrict__ Kp,
    const unsigned short* __restrict__ Vt, float* __restrict__ YA) {
    __shared__ __align__(16) unsigned short Ks[32][136];    // [m][d]
    __shared__ __align__(16) unsigned short Vs[128][40];    // [c][m-chunk]
    __shared__ __align__(16) unsigned short Pt[4][16][40];  // per-wave [q][m]

    int t = threadIdx.x;
    int w = t >> 6;
    int lane = t & 63;
    int ln = lane & 15;
    int quad = lane >> 4;
    int b = blockIdx.y;
    int qbase_wg = blockIdx.x * 128;

    const unsigned short* qb = Q + ((size_t)b * N_ + qbase_wg + w * 32) * 128;
    short8 qfrag[2][4];
#pragma unroll
    for (int qt = 0; qt < 2; qt++)
#pragma unroll
        for (int dc = 0; dc < 4; dc++)
            qfrag[qt][dc] =
                *(const short8*)&qb[(size_t)(qt * 16 + ln) * 128 + dc * 32 + quad * 8];

    float4v O[2][8];
#pragma unroll
    for (int qt = 0; qt < 2; qt++)
#pragma unroll
        for (int ct = 0; ct < 8; ct++) O[qt][ct] = (float4v){0.f, 0.f, 0.f, 0.f};
    float m_run[2] = {-1e30f, -1e30f};
    float l_run[2] = {0.f, 0.f};

    const unsigned short* kg0 = Kp + (size_t)b * M_ * 128;
    const unsigned short* vg0 = Vt + (size_t)b * 128 * M_;

    for (int kc = 0; kc < 32; kc++) {
        const unsigned short* kg = kg0 + (size_t)kc * 32 * 128;
        const unsigned short* vg = vg0 + kc * 32;
        int i0 = t, i1 = t + 256;
        uint4 gk0 = *(const uint4*)(kg + (size_t)i0 * 8);
        uint4 gk1 = *(const uint4*)(kg + (size_t)i1 * 8);
        uint4 gv0 = *(const uint4*)(vg + (size_t)(i0 >> 2) * M_ + (i0 & 3) * 8);
        uint4 gv1 = *(const uint4*)(vg + (size_t)(i1 >> 2) * M_ + (i1 & 3) * 8);
        __syncthreads();
        *(uint4*)&Ks[i0 >> 4][(i0 & 15) * 8] = gk0;   // 16 chunks of 8 per 128-row
        *(uint4*)&Ks[i1 >> 4][(i1 & 15) * 8] = gk1;
        *(uint4*)&Vs[i0 >> 2][(i0 & 3) * 8] = gv0;
        *(uint4*)&Vs[i1 >> 2][(i1 & 3) * 8] = gv1;
        __syncthreads();

        short8 vf[8];
#pragma unroll
        for (int ct = 0; ct < 8; ct++)
            vf[ct] = *(const short8*)&Vs[ct * 16 + ln][quad * 8];

        float4v S[2][2];
#pragma unroll
        for (int qt = 0; qt < 2; qt++)
#pragma unroll
            for (int mh = 0; mh < 2; mh++) S[qt][mh] = (float4v){0.f, 0.f, 0.f, 0.f};
#pragma unroll
        for (int dc = 0; dc < 4; dc++) {
#pragma unroll
            for (int mh = 0; mh < 2; mh++) {
                short8 kf = *(const short8*)&Ks[mh * 16 + ln][dc * 32 + quad * 8];
#pragma unroll
                for (int qt = 0; qt < 2; qt++)
                    S[qt][mh] = __builtin_amdgcn_mfma_f32_16x16x32_bf16(
                        kf, qfrag[qt][dc], S[qt][mh], 0, 0, 0);
            }
        }

#pragma unroll
        for (int qt = 0; qt < 2; qt++) {
            float mx = S[qt][0][0];
#pragma unroll
            for (int r = 1; r < 4; r++) mx = fmaxf(mx, S[qt][0][r]);
#pragma unroll
            for (int r = 0; r < 4; r++) mx = fmaxf(mx, S[qt][1][r]);
            mx = fmaxf(mx, __shfl_xor(mx, 16));
            mx = fmaxf(mx, __shfl_xor(mx, 32));
            float nm = fmaxf(m_run[qt], mx);
            float al = __expf(m_run[qt] - nm);
            m_run[qt] = nm;
            float ps = 0.f;
            unsigned int pk[2][2];
#pragma unroll
            for (int mh = 0; mh < 2; mh++) {
                float p0 = __expf(S[qt][mh][0] - nm);
                float p1 = __expf(S[qt][mh][1] - nm);
                float p2 = __expf(S[qt][mh][2] - nm);
                float p3 = __expf(S[qt][mh][3] - nm);
                ps += p0 + p1 + p2 + p3;
                pk[mh][0] = (unsigned int)f2bf(p0) | ((unsigned int)f2bf(p1) << 16);
                pk[mh][1] = (unsigned int)f2bf(p2) | ((unsigned int)f2bf(p3) << 16);
            }
            ps += __shfl_xor(ps, 16);
            ps += __shfl_xor(ps, 32);
            l_run[qt] = l_run[qt] * al + ps;
#pragma unroll
            for (int mh = 0; mh < 2; mh++) {
                uint2 wv = {pk[mh][0], pk[mh][1]};
                *(uint2*)&Pt[w][ln][mh * 16 + quad * 4] = wv;
            }
            if (__any(al < 1.0f)) {
#pragma unroll
                for (int ct = 0; ct < 8; ct++)
#pragma unroll
                    for (int r = 0; r < 4; r++) O[qt][ct][r] *= al;
            }
            short8 pf = *(const short8*)&Pt[w][ln][quad * 8];
#pragma unroll
            for (int ct = 0; ct < 8; ct++)
                O[qt][ct] = __builtin_amdgcn_mfma_f32_16x16x32_bf16(
                    vf[ct], pf, O[qt][ct], 0, 0, 0);
        }
    }

#pragma unroll
    for (int qt = 0; qt < 2; qt++) {
        float inv = 1.0f / l_run[qt];
        float* yb = YA + ((size_t)b * N_ + qbase_wg + w * 32 + qt * 16 + ln) * 128;
#pragma unroll
        for (int ct = 0; ct < 8; ct++) {
            float4 ov = {O[qt][ct][0] * inv, O[qt][ct][1] * inv,
                         O[qt][ct][2] * inv, O[qt][ct][3] * inv};
            *(float4*)&yb[ct * 16 + quad * 4] = ov;
        }
    }
}

// ---------------- k4: W-conv GEMM y2[b][o][n] (bf16 out) + BN stats
__global__ __launch_bounds__(256) void k4_convw(
    const float* __restrict__ Y, const float* __restrict__ ww,
    const float* __restrict__ wb, unsigned short* __restrict__ Y2,
    float* __restrict__ stats) {
    __shared__ float wsT[64][68];
    __shared__ float ys[64][68];
    int t = threadIdx.x;
    int ntile = blockIdx.x;
    int ot = blockIdx.y;
    int b = blockIdx.z;

    const float* wbase = ww + (size_t)ot * 64 * 128;
    const float* ybase = Y + ((size_t)b * N_ + ntile * 64) * 128;

    int i = t >> 4;
    int m = t & 15;
    float acc[4][4];
#pragma unroll
    for (int j = 0; j < 4; j++)
#pragma unroll
        for (int k = 0; k < 4; k++) acc[j][k] = 0.f;

    for (int c0 = 0; c0 < 128; c0 += 64) {
        __syncthreads();
#pragma unroll
        for (int r = 0; r < 4; r++) {
            int id = t + 256 * r;
            int row = id >> 4, col4 = (id & 15) * 4;
            *(float4*)&wsT[row][col4] =
                *(const float4*)&wbase[(size_t)row * 128 + c0 + col4];
            *(float4*)&ys[row][col4] =
                *(const float4*)&ybase[(size_t)row * 128 + c0 + col4];
        }
        __syncthreads();
#pragma unroll 4
        for (int c4 = 0; c4 < 64; c4 += 4) {
            float4 wv[4], yv[4];
#pragma unroll
            for (int j = 0; j < 4; j++) wv[j] = *(float4*)&wsT[i + 16 * j][c4];
#pragma unroll
            for (int k = 0; k < 4; k++) yv[k] = *(float4*)&ys[m + 16 * k][c4];
#pragma unroll
            for (int j = 0; j < 4; j++)
#pragma unroll
                for (int k = 0; k < 4; k++)
                    acc[j][k] += wv[j].x * yv[k].x + wv[j].y * yv[k].y +
                                 wv[j].z * yv[k].z + wv[j].w * yv[k].w;
        }
    }

    float s1[4], s2[4];
#pragma unroll
    for (int j = 0; j < 4; j++) {
        float bv = wb[ot * 64 + i + 16 * j];
        s1[j] = 0.f; s2[j] = 0.f;
#pragma unroll
        for (int k = 0; k < 4; k++) {
            float v = acc[j][k] + bv;
            acc[j][k] = v;
            s1[j] += v; s2[j] += v * v;
        }
    }
#pragma unroll
    for (int d = 1; d < 16; d <<= 1) {
#pragma unroll
        for (int j = 0; j < 4; j++) {
            s1[j] += __shfl_xor(s1[j], d);
            s2[j] += __shfl_xor(s2[j], d);
        }
    }
    if (m == 0) {
#pragma unroll
        for (int j = 0; j < 4; j++) {
            int o = ot * 64 + i + 16 * j;
            atomicAdd(&stats[o], s1[j]);
            atomicAdd(&stats[256 + o], s2[j]);
        }
    }
    unsigned short* obase = Y2 + (size_t)b * C_ * N_;
#pragma unroll
    for (int j = 0; j < 4; j++)
#pragma unroll
        for (int k = 0; k < 4; k++)
            obase[(size_t)(ot * 64 + i + 16 * j) * N_ + ntile * 64 + m + 16 * k] =
                f2bf(acc[j][k]);
}

// ---------------- k6: BN + affine + residual (Y2 bf16 in, fp32 out)
__global__ void k6_bn(const unsigned short* __restrict__ Y2,
                      const float* __restrict__ x,
                      const float* __restrict__ stats,
                      const float* __restrict__ gamma, const float* __restrict__ beta,
                      float* __restrict__ outp) {
    int idx = blockIdx.x * 256 + threadIdx.x;
    size_t base = (size_t)idx * 8;
    int o = (int)((base >> 12) & 255);
    const float cnt = (float)(B_ * N_);
    float mean = stats[o] / cnt;
    float var = stats[256 + o] / cnt - mean * mean;
    float scale = gamma[o] * rsqrtf(var + EPS_BN);
    float shift = beta[o] - mean * scale;
    uint4 yv = *(const uint4*)&Y2[base];
    const unsigned int* yw = &yv.x;
    float4 x0 = *(const float4*)&x[base];
    float4 x1 = *(const float4*)&x[base + 4];
    float y[8];
#pragma unroll
    for (int j = 0; j < 4; j++) {
        y[2 * j] = bf2f((unsigned short)(yw[j] & 0xffff));
        y[2 * j + 1] = bf2f((unsigned short)(yw[j] >> 16));
    }
    float4 o0 = {y[0] * scale + shift + x0.x, y[1] * scale + shift + x0.y,
                 y[2] * scale + shift + x0.z, y[3] * scale + shift + x0.w};
    float4 o1 = {y[4] * scale + shift + x1.x, y[5] * scale + shift + x1.y,
                 y[6] * scale + shift + x1.z, y[7] * scale + shift + x1.w};
    *(float4*)&outp[base] = o0;
    *(float4*)&outp[base + 4] = o1;
}

extern "C" void kernel_launch(void* const* d_in, const int* in_sizes, int n_in,
                              void* d_out, int out_size, void* d_ws, size_t ws_size,
                              hipStream_t stream) {
    const float* x    = (const float*)d_in[0];
    const float* g_w  = (const float*)d_in[1];
    const float* g_b  = (const float*)d_in[2];
    const float* th_w = (const float*)d_in[3];
    const float* th_b = (const float*)d_in[4];
    const float* ph_w = (const float*)d_in[5];
    const float* ph_b = (const float*)d_in[6];
    const float* w_w  = (const float*)d_in[7];
    const float* w_b  = (const float*)d_in[8];
    const float* gam  = (const float*)d_in[9];
    const float* bet  = (const float*)d_in[10];

    char* ws = (char*)d_ws;
    float*          wT  = (float*)(ws + OFF_WT);
    unsigned short* Qb  = (unsigned short*)(ws + OFF_Q);
    unsigned short* PHI = (unsigned short*)(ws + OFF_PHI);
    unsigned short* Gb  = (unsigned short*)(ws + OFF_G);
    unsigned short* Kp  = (unsigned short*)(ws + OFF_KP);
    unsigned short* Vt  = (unsigned short*)(ws + OFF_VT);
    float*          YA  = (float*)(ws + OFF_YA);
    float*          ST  = (float*)(ws + OFF_ST);
    unsigned short* Y2  = (unsigned short*)(ws + OFF_Y2);
    float* outp = (float*)d_out;

    hipMemsetAsync(ST, 0, 512 * sizeof(float), stream);
    k0_transpose_w<<<384, 256, 0, stream>>>(th_w, ph_w, g_w, wT);
    k1_proj<<<dim3(64, 16, 3), 256, 0, stream>>>(x, wT, th_b, ph_b, g_b, Qb, PHI, Gb);
    k2k_pool<<<1024, 256, 0, stream>>>(PHI, Kp);
    k2v_poolT<<<dim3(16, 16), 256, 0, stream>>>(Gb, Vt);
    k3_attn<<<dim3(32, 16), 256, 0, stream>>>(Qb, Kp, Vt, YA);
    k4_convw<<<dim3(64, 4, 16), 256, 0, stream>>>(YA, w_w, w_b, Y2, ST);
    k6_bn<<<8192, 256, 0, stream>>>(Y2, x, ST, gam, bet, outp);
}